// Round 3
// baseline (244.433 us; speedup 1.0000x reference)
//
#include <hip/hip_runtime.h>
#include <stdint.h>

#define NB 4
#define NH 16
#define DKH 64
#define DMODEL 1024
#define SEQ 1024
#define SCALE 0.125f
#define NEG_INF -1.0e9f
#define K2E 0.18033688011112042f  // SCALE * log2(e): softmax done in exp2 domain

typedef __bf16 bf16_t;
typedef __bf16 bf16x8 __attribute__((ext_vector_type(8)));
typedef __bf16 bf16x4v __attribute__((ext_vector_type(4)));
typedef float f32x4 __attribute__((ext_vector_type(4)));

typedef const uint32_t __attribute__((address_space(1)))* gas_ptr;
typedef uint32_t __attribute__((address_space(3)))* las_ptr;

// async global->LDS, 16B per lane, dest = wave-uniform base + lane*16
__device__ __forceinline__ void gload_lds16(const void* g, void* l) {
  __builtin_amdgcn_global_load_lds((gas_ptr)g, (las_ptr)l, 16, 0, 0);
}

// T2 XOR swizzle for [R][64] bf16 tiles (128B rows): element col ^= (row&7)<<3.
// Staging keeps LDS dest linear and pre-swizzles the GLOBAL source column;
// all LDS reads / reg->LDS writes apply the same XOR (both-sides involution).

// ---------------- f32 -> bf16 conversion (select tensor by blockIdx.y) ----
__global__ void cvt_multi(const float* __restrict__ i0, const float* __restrict__ i1,
                          const float* __restrict__ i2, const float* __restrict__ i3,
                          const float* __restrict__ i4, const float* __restrict__ i5,
                          bf16_t* o0, bf16_t* o1, bf16_t* o2, bf16_t* o3, bf16_t* o4, bf16_t* o5,
                          int n) {
  const int t = blockIdx.y;
  const float* in = (t == 0) ? i0 : (t == 1) ? i1 : (t == 2) ? i2 : (t == 3) ? i3 : (t == 4) ? i4 : i5;
  bf16_t* out = (t == 0) ? o0 : (t == 1) ? o1 : (t == 2) ? o2 : (t == 3) ? o3 : (t == 4) ? o4 : o5;
  const int idx = (blockIdx.x * 256 + threadIdx.x) * 4;
  if (idx >= n) return;
  const float4 v = *(const float4*)(in + idx);
  bf16x4v p;
  p[0] = (bf16_t)v.x; p[1] = (bf16_t)v.y; p[2] = (bf16_t)v.z; p[3] = (bf16_t)v.w;
  *(bf16x4v*)(out + idx) = p;
}

// ---------------- GEMM: Y = A @ W^T + bias (double-buffered, T3-minimum) ---
// Tile 128x64, BK=64, 4 waves (2x2). MODE 0: bf16 [B,H,L,DK]; MODE 1: bf16
// [B,H,DK,L] (transposed); MODE 2: f32 [M,N].
template<int MODE>
__global__ void __launch_bounds__(256, 2)
gemm_bt(const bf16_t* __restrict__ A, const bf16_t* __restrict__ W,
        const float* __restrict__ bias, void* __restrict__ outp) {
  __shared__ bf16_t As[2][128 * 64];
  __shared__ bf16_t Bs[2][64 * 64];
  const int tid = threadIdx.x;
  const int lane = tid & 63;
  const int w = tid >> 6;
  const int wm = w >> 1, wn = w & 1;
  const int g = lane >> 4, c = lane & 15;
  const int bid = blockIdx.x;
  const int bm = bid >> 4, bn = bid & 15;     // 32 x 16 tiles
  const int m0 = bm * 128, n0 = bn * 64;
  const int lrow = lane >> 3;
  const int lcol = ((lane & 7) * 8) ^ ((lane >> 3) << 3);  // pre-swizzled source col
  const int sc = (c & 7) << 3;                             // read-side XOR

  f32x4 acc[4][2] = {};

  auto stage = [&](int buf, int kt) {
#pragma unroll
    for (int p = 0; p < 4; ++p) {
      const int row = w * 32 + p * 8;
      gload_lds16(A + (size_t)(m0 + row + lrow) * DMODEL + kt + lcol, &As[buf][row * 64]);
    }
#pragma unroll
    for (int p = 0; p < 2; ++p) {
      const int row = w * 16 + p * 8;
      gload_lds16(W + (size_t)(n0 + row + lrow) * DMODEL + kt + lcol, &Bs[buf][row * 64]);
    }
  };

  stage(0, 0);
  __syncthreads();

  for (int t = 0; t < 16; ++t) {
    const int cur = t & 1;
    if (t < 15) stage(cur ^ 1, (t + 1) * 64);   // prefetch next K-tile (stays in flight)

    bf16x8 af[4][2], bfr[2][2];
#pragma unroll
    for (int i = 0; i < 4; ++i)
#pragma unroll
      for (int kk = 0; kk < 2; ++kk)
        af[i][kk] = *(const bf16x8*)&As[cur][(wm * 64 + i * 16 + c) * 64 + ((kk * 32 + g * 8) ^ sc)];
#pragma unroll
    for (int j = 0; j < 2; ++j)
#pragma unroll
      for (int kk = 0; kk < 2; ++kk)
        bfr[j][kk] = *(const bf16x8*)&Bs[cur][(wn * 32 + j * 16 + c) * 64 + ((kk * 32 + g * 8) ^ sc)];
#pragma unroll
    for (int i = 0; i < 4; ++i)
#pragma unroll
      for (int j = 0; j < 2; ++j) {
        acc[i][j] = __builtin_amdgcn_mfma_f32_16x16x32_bf16(af[i][0], bfr[j][0], acc[i][j], 0, 0, 0);
        acc[i][j] = __builtin_amdgcn_mfma_f32_16x16x32_bf16(af[i][1], bfr[j][1], acc[i][j], 0, 0, 0);
      }
    __syncthreads();   // single drain per iter: prefetched loads landed, reads done
  }

  float bv2[2];
#pragma unroll
  for (int j = 0; j < 2; ++j) bv2[j] = bias[n0 + wn * 32 + j * 16 + c];

#pragma unroll
  for (int i = 0; i < 4; ++i) {
    const int mrow = m0 + wm * 64 + i * 16 + g * 4;   // C-layout: row = g*4 + r
    const int b_ = mrow >> 10, l_ = mrow & 1023;
#pragma unroll
    for (int j = 0; j < 2; ++j) {
      const int n = n0 + wn * 32 + j * 16 + c;        // C-layout: col = lane&15
      if (MODE == 2) {
        float* o = (float*)outp;
#pragma unroll
        for (int r = 0; r < 4; ++r)
          o[(size_t)(mrow + r) * DMODEL + n] = acc[i][j][r] + bv2[j];
      } else if (MODE == 0) {
        bf16_t* o = (bf16_t*)outp;
        const int h_ = n >> 6, dk_ = n & 63;
#pragma unroll
        for (int r = 0; r < 4; ++r)
          o[((size_t)(b_ * NH + h_) * SEQ + l_ + r) * DKH + dk_] =
              (bf16_t)(acc[i][j][r] + bv2[j]);
      } else { // MODE 1: transposed [B,H,DK,L]; 4 consecutive l -> packed 8B store
        bf16_t* o = (bf16_t*)outp;
        const int h_ = n >> 6, dk_ = n & 63;
        bf16x4v pk;
#pragma unroll
        for (int r = 0; r < 4; ++r) pk[r] = (bf16_t)(acc[i][j][r] + bv2[j]);
        *(bf16x4v*)&o[((size_t)(b_ * NH + h_) * DKH + dk_) * SEQ + l_] = pk;
      }
    }
  }
}

// ---------------- fused dual flash attention ------------------------------
// K/RK double-buffered in LDS (swizzled); V/RV read global->register
// fragments directly (vT layout is already the PV B-operand layout).
// Softmax in exp2 domain. Pw = per-wave [32][64] bf16 LDS (swizzled).
__device__ __forceinline__ void attn_step(
    const bf16_t* __restrict__ Kt, const bf16x8 (&vfr)[4][2],
    bf16_t* __restrict__ Pw, const bf16x8 (&qf)[2][2], const int (&mk)[4],
    f32x4 (&m_s)[2], f32x4 (&l_s)[2], f32x4 (&o_s)[2][4], int lane) {
  const int g = lane >> 4, c = lane & 15;
  const int sc = (c & 7) << 3;

  bf16x8 kfr[4][2];
#pragma unroll
  for (int f = 0; f < 4; ++f)
#pragma unroll
    for (int kk = 0; kk < 2; ++kk)
      kfr[f][kk] = *(const bf16x8*)&Kt[(f * 16 + c) * 64 + ((kk * 32 + g * 8) ^ sc)];

  f32x4 s[2][4];
#pragma unroll
  for (int i = 0; i < 2; ++i)
#pragma unroll
    for (int f = 0; f < 4; ++f) {
      f32x4 a = {0.f, 0.f, 0.f, 0.f};
      a = __builtin_amdgcn_mfma_f32_16x16x32_bf16(qf[i][0], kfr[f][0], a, 0, 0, 0);
      a = __builtin_amdgcn_mfma_f32_16x16x32_bf16(qf[i][1], kfr[f][1], a, 0, 0, 0);
      s[i][f] = a;
    }

  // scale into exp2 domain + mask (masked -> NEG_INF; kv=0 is always valid so
  // the online rescale-by-zero self-heals any all-masked prefix tile)
#pragma unroll
  for (int i = 0; i < 2; ++i)
#pragma unroll
    for (int f = 0; f < 4; ++f)
#pragma unroll
      for (int r = 0; r < 4; ++r)
        s[i][f][r] = (mk[f] == 0) ? NEG_INF : s[i][f][r] * K2E;

#pragma unroll
  for (int i = 0; i < 2; ++i) {
    f32x4 tm = s[i][0];
#pragma unroll
    for (int f = 1; f < 4; ++f)
#pragma unroll
      for (int r = 0; r < 4; ++r) tm[r] = fmaxf(tm[r], s[i][f][r]);
#pragma unroll
    for (int d = 1; d < 16; d <<= 1)
#pragma unroll
      for (int r = 0; r < 4; ++r) tm[r] = fmaxf(tm[r], __shfl_xor(tm[r], d));

    f32x4 mnew, sf;
#pragma unroll
    for (int r = 0; r < 4; ++r) {
      mnew[r] = fmaxf(m_s[i][r], tm[r]);
      sf[r] = __builtin_amdgcn_exp2f(m_s[i][r] - mnew[r]);
    }
    m_s[i] = mnew;

    f32x4 psum = {0.f, 0.f, 0.f, 0.f};
#pragma unroll
    for (int f = 0; f < 4; ++f)
#pragma unroll
      for (int r = 0; r < 4; ++r) {
        const float p = __builtin_amdgcn_exp2f(s[i][f][r] - mnew[r]);
        s[i][f][r] = p;
        psum[r] += p;
      }
    // l kept as per-lane partial sum (sf is lane-uniform) -> one reduce at end
#pragma unroll
    for (int r = 0; r < 4; ++r) l_s[i][r] = l_s[i][r] * sf[r] + psum[r];
#pragma unroll
    for (int jd = 0; jd < 4; ++jd)
#pragma unroll
      for (int r = 0; r < 4; ++r) o_s[i][jd][r] *= sf[r];

    // P -> LDS (row-major [32 q][64 kv], swizzled) for MFMA A-fragment reads
#pragma unroll
    for (int f = 0; f < 4; ++f)
#pragma unroll
      for (int r = 0; r < 4; ++r)
        Pw[(i * 16 + g * 4 + r) * 64 + ((f * 16 + c) ^ (((g * 4 + r) & 7) << 3))] =
            (bf16_t)s[i][f][r];
  }

  // O += P @ V  (V fragments already in registers)
#pragma unroll
  for (int i = 0; i < 2; ++i) {
    bf16x8 pa[2];
#pragma unroll
    for (int kk = 0; kk < 2; ++kk)
      pa[kk] = *(const bf16x8*)&Pw[(i * 16 + c) * 64 + ((kk * 32 + g * 8) ^ sc)];
#pragma unroll
    for (int jd = 0; jd < 4; ++jd) {
      o_s[i][jd] = __builtin_amdgcn_mfma_f32_16x16x32_bf16(pa[0], vfr[jd][0], o_s[i][jd], 0, 0, 0);
      o_s[i][jd] = __builtin_amdgcn_mfma_f32_16x16x32_bf16(pa[1], vfr[jd][1], o_s[i][jd], 0, 0, 0);
    }
  }
}

__global__ void __launch_bounds__(256, 2)
attn_kernel(const bf16_t* __restrict__ q, const bf16_t* __restrict__ k,
            const bf16_t* __restrict__ rk, const bf16_t* __restrict__ vT,
            const bf16_t* __restrict__ rvT, const int* __restrict__ mask,
            bf16_t* __restrict__ x) {
  __shared__ bf16_t Ks[2][64 * 64], RKs[2][64 * 64];   // double-buffered (32 KB)
  __shared__ bf16_t Ps[4][32 * 64];                    // per-wave P (16 KB)

  const int tid = threadIdx.x;
  const int lane = tid & 63;
  const int w = tid >> 6;
  const int g = lane >> 4, c = lane & 15;
  const int bid = blockIdx.x;
  const int qt = bid & 7;
  const int bh = bid >> 3;
  const int b = bh >> 4, h = bh & 15;
  const int q0 = qt * 128;

  const bf16_t* qp = q + (size_t)bh * SEQ * DKH;
  const bf16_t* kp = k + (size_t)bh * SEQ * DKH;
  const bf16_t* rkp = rk + (size_t)bh * SEQ * DKH;
  const bf16_t* vp = vT + (size_t)bh * DKH * SEQ;
  const bf16_t* rvp = rvT + (size_t)bh * DKH * SEQ;
  const int* mp = mask + b * SEQ;
  const int lrow = lane >> 3;
  const int lcol = ((lane & 7) * 8) ^ ((lane >> 3) << 3);  // pre-swizzled source col

  auto stage_k = [&](int buf, int kv0) {
#pragma unroll
    for (int p = 0; p < 2; ++p) {
      const int row = w * 16 + p * 8;
      gload_lds16(kp  + (size_t)(kv0 + row + lrow) * DKH + lcol, &Ks[buf][row * 64]);
      gload_lds16(rkp + (size_t)(kv0 + row + lrow) * DKH + lcol, &RKs[buf][row * 64]);
    }
  };

  // Q fragments in registers (wave owns 32 q-rows)
  bf16x8 qf[2][2];
#pragma unroll
  for (int i = 0; i < 2; ++i)
#pragma unroll
    for (int kk = 0; kk < 2; ++kk)
      qf[i][kk] = *(const bf16x8*)(qp + (size_t)(q0 + w * 32 + i * 16 + c) * DKH + kk * 32 + g * 8);

  f32x4 ov[2][4] = {}, orl[2][4] = {};
  f32x4 mv[2], lv[2], mr[2], lr[2];
#pragma unroll
  for (int i = 0; i < 2; ++i) {
    mv[i] = f32x4{NEG_INF, NEG_INF, NEG_INF, NEG_INF};
    mr[i] = mv[i];
    lv[i] = f32x4{0.f, 0.f, 0.f, 0.f};
    lr[i] = lv[i];
  }

  stage_k(0, 0);
  __syncthreads();

  for (int t = 0; t < 16; ++t) {
    const int kv0 = t * 64;
    const int cur = t & 1;

    // V/RV fragments + mask for tile t: issued FIRST so the later prefetch's
    // vmcnt entries stay outstanding when the compiler waits for these.
    bf16x8 vfr[4][2], rvfr[4][2];
#pragma unroll
    for (int jd = 0; jd < 4; ++jd)
#pragma unroll
      for (int kk = 0; kk < 2; ++kk) {
        vfr[jd][kk]  = *(const bf16x8*)(vp  + (size_t)(jd * 16 + c) * SEQ + kv0 + kk * 32 + g * 8);
        rvfr[jd][kk] = *(const bf16x8*)(rvp + (size_t)(jd * 16 + c) * SEQ + kv0 + kk * 32 + g * 8);
      }
    int mk[4];
#pragma unroll
    for (int f = 0; f < 4; ++f) mk[f] = mp[kv0 + f * 16 + c];

    if (t < 15) stage_k(cur ^ 1, kv0 + 64);   // prefetch next K/RK tile

    attn_step(Ks[cur],  vfr,  Ps[w], qf, mk, mv, lv, ov,  lane);
    attn_step(RKs[cur], rvfr, Ps[w], qf, mk, mr, lr, orl, lane);
    __syncthreads();   // single drain per iter; prefetched loads now landed
  }

  // reduce the per-lane partial softmax denominators across the 16 columns
#pragma unroll
  for (int i = 0; i < 2; ++i)
#pragma unroll
    for (int d = 1; d < 16; d <<= 1)
#pragma unroll
      for (int r = 0; r < 4; ++r) {
        lv[i][r] += __shfl_xor(lv[i][r], d);
        lr[i][r] += __shfl_xor(lr[i][r], d);
      }

  bf16_t* xb = x + (size_t)b * SEQ * DMODEL + (size_t)h * DKH;
#pragma unroll
  for (int i = 0; i < 2; ++i) {
    f32x4 rlv, rlr;
#pragma unroll
    for (int r = 0; r < 4; ++r) { rlv[r] = 1.0f / lv[i][r]; rlr[r] = 1.0f / lr[i][r]; }
#pragma unroll
    for (int jd = 0; jd < 4; ++jd)
#pragma unroll
      for (int r = 0; r < 4; ++r) {
        const int qrow = q0 + w * 32 + i * 16 + g * 4 + r;
        const float val = ov[i][jd][r] * rlv[r] + orl[i][jd][r] * rlr[r];
        xb[(size_t)qrow * DMODEL + jd * 16 + c] = (bf16_t)val;
      }
  }
}

// ---------------- host launch ---------------------------------------------
extern "C" void kernel_launch(void* const* d_in, const int* in_sizes, int n_in,
                              void* d_out, int out_size, void* d_ws, size_t ws_size,
                              hipStream_t stream) {
  (void)in_sizes; (void)n_in; (void)out_size; (void)ws_size;
  const float* query = (const float*)d_in[0];
  const float* key_  = (const float*)d_in[1];
  const float* value = (const float*)d_in[2];
  const float* weak  = (const float*)d_in[3];
  const int*   mask  = (const int*)d_in[4];
  const float* Wq  = (const float*)d_in[5];  const float* bq  = (const float*)d_in[6];
  const float* Wk  = (const float*)d_in[7];  const float* bk  = (const float*)d_in[8];
  const float* Wv  = (const float*)d_in[9];  const float* bv  = (const float*)d_in[10];
  const float* Wrk = (const float*)d_in[11]; const float* brk = (const float*)d_in[12];
  const float* Wrv = (const float*)d_in[13]; const float* brv = (const float*)d_in[14];
  const float* Wo  = (const float*)d_in[15]; const float* bo  = (const float*)d_in[16];

  char* ws = (char*)d_ws;
  size_t off = 0;
  auto alloc = [&](size_t bytes) {
    void* p = ws + off;
    off += (bytes + 255) & ~(size_t)255;
    return p;
  };
  const size_t SZ_X = (size_t)NB * SEQ * DMODEL * sizeof(bf16_t); // 8 MB
  const size_t SZ_W = (size_t)DMODEL * DMODEL * sizeof(bf16_t);   // 2 MB

  bf16_t* Xq = (bf16_t*)alloc(SZ_X);
  bf16_t* Xk = (bf16_t*)alloc(SZ_X);
  bf16_t* Xv = (bf16_t*)alloc(SZ_X);
  bf16_t* Xr = (bf16_t*)alloc(SZ_X);
  bf16_t* Wqb  = (bf16_t*)alloc(SZ_W);
  bf16_t* Wkb  = (bf16_t*)alloc(SZ_W);
  bf16_t* Wvb  = (bf16_t*)alloc(SZ_W);
  bf16_t* Wrkb = (bf16_t*)alloc(SZ_W);
  bf16_t* Wrvb = (bf16_t*)alloc(SZ_W);
  bf16_t* Wob  = (bf16_t*)alloc(SZ_W);
  bf16_t* qh   = (bf16_t*)alloc(SZ_X);
  bf16_t* kh   = (bf16_t*)alloc(SZ_X);
  bf16_t* rkh  = (bf16_t*)alloc(SZ_X);
  bf16_t* vTh  = (bf16_t*)alloc(SZ_X);
  bf16_t* rvTh = (bf16_t*)alloc(SZ_X);
  bf16_t* xh   = (bf16_t*)alloc(SZ_X);

  // f32 -> bf16
  cvt_multi<<<dim3(4096, 4), 256, 0, stream>>>(query, key_, value, weak, nullptr, nullptr,
                                               Xq, Xk, Xv, Xr, nullptr, nullptr,
                                               NB * SEQ * DMODEL);
  cvt_multi<<<dim3(1024, 6), 256, 0, stream>>>(Wq, Wk, Wv, Wrk, Wrv, Wo,
                                               Wqb, Wkb, Wvb, Wrkb, Wrvb, Wob,
                                               DMODEL * DMODEL);

  // projections (512 blocks = 32 m-tiles x 16 n-tiles)
  gemm_bt<0><<<dim3(512), 256, 0, stream>>>(Xq, Wqb, bq, qh);
  gemm_bt<0><<<dim3(512), 256, 0, stream>>>(Xk, Wkb, bk, kh);
  gemm_bt<0><<<dim3(512), 256, 0, stream>>>(Xr, Wrkb, brk, rkh);
  gemm_bt<1><<<dim3(512), 256, 0, stream>>>(Xv, Wvb, bv, vTh);
  gemm_bt<1><<<dim3(512), 256, 0, stream>>>(Xr, Wrvb, brv, rvTh);

  // fused dual attention: 4 b * 16 h * 8 q-tiles = 512 blocks
  attn_kernel<<<dim3(512), 256, 0, stream>>>(qh, kh, rkh, vTh, rvTh, mask, xh);

  // output projection -> f32 d_out
  gemm_bt<2><<<dim3(512), 256, 0, stream>>>(xh, Wob, bo, d_out);
}

// Round 4
// 215.268 us; speedup vs baseline: 1.1355x; 1.1355x over previous
//
#include <hip/hip_runtime.h>
#include <stdint.h>

#define NB 4
#define NH 16
#define DKH 64
#define DMODEL 1024
#define SEQ 1024
#define SCALE 0.125f
#define NEG_INF -1.0e9f
#define K2E 0.18033688011112042f  // SCALE * log2(e): softmax in exp2 domain

typedef __bf16 bf16_t;
typedef __bf16 bf16x8 __attribute__((ext_vector_type(8)));
typedef __bf16 bf16x4v __attribute__((ext_vector_type(4)));
typedef float f32x4 __attribute__((ext_vector_type(4)));

typedef const uint32_t __attribute__((address_space(1)))* gas_ptr;
typedef uint32_t __attribute__((address_space(3)))* las_ptr;

// async global->LDS, 16B per lane, dest = wave-uniform base + lane*16
__device__ __forceinline__ void gload_lds16(const void* g, void* l) {
  __builtin_amdgcn_global_load_lds((gas_ptr)g, (las_ptr)l, 16, 0, 0);
}

// T2 XOR swizzle for [R][64] bf16 tiles (128B rows): element col ^= (row&7)<<3.
// Staging keeps LDS dest linear and pre-swizzles the GLOBAL source column;
// all LDS reads / reg->LDS writes apply the same XOR (both-sides involution).
// Proven: SQ_LDS_BANK_CONFLICT 1.99e7 -> 0 (R1->R2).

// ---------------- f32 -> bf16 conversion (select tensor by blockIdx.y) ----
__global__ void cvt_multi(const float* __restrict__ i0, const float* __restrict__ i1,
                          const float* __restrict__ i2, const float* __restrict__ i3,
                          const float* __restrict__ i4, const float* __restrict__ i5,
                          bf16_t* o0, bf16_t* o1, bf16_t* o2, bf16_t* o3, bf16_t* o4, bf16_t* o5,
                          int n) {
  const int t = blockIdx.y;
  const float* in = (t == 0) ? i0 : (t == 1) ? i1 : (t == 2) ? i2 : (t == 3) ? i3 : (t == 4) ? i4 : i5;
  bf16_t* out = (t == 0) ? o0 : (t == 1) ? o1 : (t == 2) ? o2 : (t == 3) ? o3 : (t == 4) ? o4 : o5;
  const int idx = (blockIdx.x * 256 + threadIdx.x) * 4;
  if (idx >= n) return;
  const float4 v = *(const float4*)(in + idx);
  bf16x4v p;
  p[0] = (bf16_t)v.x; p[1] = (bf16_t)v.y; p[2] = (bf16_t)v.z; p[3] = (bf16_t)v.w;
  *(bf16x4v*)(out + idx) = p;
}

// ---------------- grouped projection GEMM ---------------------------------
// 5 segments (q,k,v,rk,rv), each Y = A @ W^T + bias, [4096x1024]x[1024x1024].
// Tile 128x64, BK=64, 4 waves (2x2), single-buffered LDS (24KB).
// X segments contiguous at Xbase (stride NXE; seg rk/rv share Xr), W segments
// contiguous at Wbase, outputs contiguous at Obase. seg 2 (v) and 4 (rv)
// write transposed head-split [B,H,DK,L]; others [B,H,L,DK].
#define NXE ((size_t)NB * SEQ * DMODEL)      // elements per X/out segment
#define NWE ((size_t)DMODEL * DMODEL)
__global__ void __launch_bounds__(256, 4)
proj_gemm(const bf16_t* __restrict__ Xbase, const bf16_t* __restrict__ Wbase,
          bf16_t* __restrict__ Obase,
          const float* __restrict__ b0, const float* __restrict__ b1,
          const float* __restrict__ b2, const float* __restrict__ b3,
          const float* __restrict__ b4) {
  __shared__ bf16_t As[128 * 64];
  __shared__ bf16_t Bs[64 * 64];
  const int tid = threadIdx.x;
  const int lane = tid & 63;
  const int w = tid >> 6;
  const int wm = w >> 1, wn = w & 1;
  const int g = lane >> 4, c = lane & 15;
  // T1 bijective XCD swizzle: 2560 % 8 == 0, cpx = 320
  const int bid = blockIdx.x;
  const int lid = (bid & 7) * 320 + (bid >> 3);
  const int seg = lid >> 9;                 // 0..4
  const int rr = lid & 511;
  const int bm = rr >> 4, bn = rr & 15;     // 32 x 16 tiles
  const int m0 = bm * 128, n0 = bn * 64;
  const int lrow = lane >> 3;
  const int lcol = ((lane & 7) * 8) ^ ((lane >> 3) << 3);  // pre-swizzled source col
  const int sc = (c & 7) << 3;                             // read-side XOR

  const bf16_t* A = Xbase + (size_t)((seg < 3) ? seg : 3) * NXE;
  const bf16_t* W = Wbase + (size_t)seg * NWE;
  const int ooff = (seg == 0) ? 0 : (seg == 1) ? 1 : (seg == 2) ? 3 : (seg == 3) ? 2 : 4;
  bf16_t* out = Obase + (size_t)ooff * NXE;
  const float* bias = (seg == 0) ? b0 : (seg == 1) ? b1 : (seg == 2) ? b2 : (seg == 3) ? b3 : b4;
  const bool tr = (seg == 2) || (seg == 4);

  f32x4 acc[4][2] = {};

  for (int kt = 0; kt < DMODEL; kt += 64) {
#pragma unroll
    for (int p = 0; p < 4; ++p) {
      const int row = w * 32 + p * 8;
      gload_lds16(A + (size_t)(m0 + row + lrow) * DMODEL + kt + lcol, &As[row * 64]);
    }
#pragma unroll
    for (int p = 0; p < 2; ++p) {
      const int row = w * 16 + p * 8;
      gload_lds16(W + (size_t)(n0 + row + lrow) * DMODEL + kt + lcol, &Bs[row * 64]);
    }
    __syncthreads();
    bf16x8 af[4][2], bfr[2][2];
#pragma unroll
    for (int i = 0; i < 4; ++i)
#pragma unroll
      for (int kk = 0; kk < 2; ++kk)
        af[i][kk] = *(const bf16x8*)&As[(wm * 64 + i * 16 + c) * 64 + ((kk * 32 + g * 8) ^ sc)];
#pragma unroll
    for (int j = 0; j < 2; ++j)
#pragma unroll
      for (int kk = 0; kk < 2; ++kk)
        bfr[j][kk] = *(const bf16x8*)&Bs[(wn * 32 + j * 16 + c) * 64 + ((kk * 32 + g * 8) ^ sc)];
#pragma unroll
    for (int i = 0; i < 4; ++i)
#pragma unroll
      for (int j = 0; j < 2; ++j) {
        acc[i][j] = __builtin_amdgcn_mfma_f32_16x16x32_bf16(af[i][0], bfr[j][0], acc[i][j], 0, 0, 0);
        acc[i][j] = __builtin_amdgcn_mfma_f32_16x16x32_bf16(af[i][1], bfr[j][1], acc[i][j], 0, 0, 0);
      }
    __syncthreads();
  }

  float bv2[2];
#pragma unroll
  for (int j = 0; j < 2; ++j) bv2[j] = bias[n0 + wn * 32 + j * 16 + c];

#pragma unroll
  for (int i = 0; i < 4; ++i) {
    const int mrow = m0 + wm * 64 + i * 16 + g * 4;   // C-layout: row = g*4 + r
    const int b_ = mrow >> 10, l_ = mrow & 1023;
#pragma unroll
    for (int j = 0; j < 2; ++j) {
      const int n = n0 + wn * 32 + j * 16 + c;        // C-layout: col = lane&15
      const int h_ = n >> 6, dk_ = n & 63;
      if (!tr) {
#pragma unroll
        for (int r = 0; r < 4; ++r)
          out[((size_t)(b_ * NH + h_) * SEQ + l_ + r) * DKH + dk_] =
              (bf16_t)(acc[i][j][r] + bv2[j]);
      } else { // transposed [B,H,DK,L]; 4 consecutive l -> packed 8B store
        bf16x4v pk;
#pragma unroll
        for (int r = 0; r < 4; ++r) pk[r] = (bf16_t)(acc[i][j][r] + bv2[j]);
        *(bf16x4v*)&out[((size_t)(b_ * NH + h_) * DKH + dk_) * SEQ + l_] = pk;
      }
    }
  }
}

// ---------------- output projection GEMM (f32 out) -------------------------
__global__ void __launch_bounds__(256, 2)
out_gemm(const bf16_t* __restrict__ A, const bf16_t* __restrict__ W,
         const float* __restrict__ bias, float* __restrict__ out) {
  __shared__ bf16_t As[128 * 64];
  __shared__ bf16_t Bs[64 * 64];
  const int tid = threadIdx.x;
  const int lane = tid & 63;
  const int w = tid >> 6;
  const int wm = w >> 1, wn = w & 1;
  const int g = lane >> 4, c = lane & 15;
  const int bid = blockIdx.x;
  const int lid = (bid & 7) * 64 + (bid >> 3);   // T1 swizzle (512 % 8 == 0)
  const int bm = lid >> 4, bn = lid & 15;
  const int m0 = bm * 128, n0 = bn * 64;
  const int lrow = lane >> 3;
  const int lcol = ((lane & 7) * 8) ^ ((lane >> 3) << 3);
  const int sc = (c & 7) << 3;

  f32x4 acc[4][2] = {};

  for (int kt = 0; kt < DMODEL; kt += 64) {
#pragma unroll
    for (int p = 0; p < 4; ++p) {
      const int row = w * 32 + p * 8;
      gload_lds16(A + (size_t)(m0 + row + lrow) * DMODEL + kt + lcol, &As[row * 64]);
    }
#pragma unroll
    for (int p = 0; p < 2; ++p) {
      const int row = w * 16 + p * 8;
      gload_lds16(W + (size_t)(n0 + row + lrow) * DMODEL + kt + lcol, &Bs[row * 64]);
    }
    __syncthreads();
    bf16x8 af[4][2], bfr[2][2];
#pragma unroll
    for (int i = 0; i < 4; ++i)
#pragma unroll
      for (int kk = 0; kk < 2; ++kk)
        af[i][kk] = *(const bf16x8*)&As[(wm * 64 + i * 16 + c) * 64 + ((kk * 32 + g * 8) ^ sc)];
#pragma unroll
    for (int j = 0; j < 2; ++j)
#pragma unroll
      for (int kk = 0; kk < 2; ++kk)
        bfr[j][kk] = *(const bf16x8*)&Bs[(wn * 32 + j * 16 + c) * 64 + ((kk * 32 + g * 8) ^ sc)];
#pragma unroll
    for (int i = 0; i < 4; ++i)
#pragma unroll
      for (int j = 0; j < 2; ++j) {
        acc[i][j] = __builtin_amdgcn_mfma_f32_16x16x32_bf16(af[i][0], bfr[j][0], acc[i][j], 0, 0, 0);
        acc[i][j] = __builtin_amdgcn_mfma_f32_16x16x32_bf16(af[i][1], bfr[j][1], acc[i][j], 0, 0, 0);
      }
    __syncthreads();
  }

  float bv2[2];
#pragma unroll
  for (int j = 0; j < 2; ++j) bv2[j] = bias[n0 + wn * 32 + j * 16 + c];
#pragma unroll
  for (int i = 0; i < 4; ++i) {
    const int mrow = m0 + wm * 64 + i * 16 + g * 4;
#pragma unroll
    for (int j = 0; j < 2; ++j) {
      const int n = n0 + wn * 32 + j * 16 + c;
#pragma unroll
      for (int r = 0; r < 4; ++r)
        out[(size_t)(mrow + r) * DMODEL + n] = acc[i][j][r] + bv2[j];
    }
  }
}

// ---------------- fused dual flash attention -------------------------------
// q-tile 64 (16 rows/wave), grid 1024 -> 4 blocks/CU (40KB LDS), all tensors
// single-buffered LDS (dbuf proven null R3: barrier drains vmcnt regardless).
__device__ __forceinline__ void attn_step(
    const bf16_t* __restrict__ Kt, const bf16_t* __restrict__ Vt,
    bf16_t* __restrict__ Pw, const bf16x8 (&qf)[2], const int (&mk)[4],
    f32x4& m_s, f32x4& l_s, f32x4 (&o_s)[4], int lane) {
  const int g = lane >> 4, c = lane & 15;
  const int sc = (c & 7) << 3;

  f32x4 s[4];
  {
    bf16x8 kfr[4][2];
#pragma unroll
    for (int f = 0; f < 4; ++f)
#pragma unroll
      for (int kk = 0; kk < 2; ++kk)
        kfr[f][kk] = *(const bf16x8*)&Kt[(f * 16 + c) * 64 + ((kk * 32 + g * 8) ^ sc)];
#pragma unroll
    for (int f = 0; f < 4; ++f) {
      f32x4 a = {0.f, 0.f, 0.f, 0.f};
      a = __builtin_amdgcn_mfma_f32_16x16x32_bf16(qf[0], kfr[f][0], a, 0, 0, 0);
      a = __builtin_amdgcn_mfma_f32_16x16x32_bf16(qf[1], kfr[f][1], a, 0, 0, 0);
      s[f] = a;
    }
  } // kfr dead here -> keeps peak VGPR under the (256,4) cap

  // scale into exp2 domain + mask (masked -> NEG_INF; kv=0 always valid)
#pragma unroll
  for (int f = 0; f < 4; ++f)
#pragma unroll
    for (int r = 0; r < 4; ++r)
      s[f][r] = (mk[f] == 0) ? NEG_INF : s[f][r] * K2E;

  f32x4 tm = s[0];
#pragma unroll
  for (int f = 1; f < 4; ++f)
#pragma unroll
    for (int r = 0; r < 4; ++r) tm[r] = fmaxf(tm[r], s[f][r]);
#pragma unroll
  for (int d = 1; d < 16; d <<= 1)
#pragma unroll
    for (int r = 0; r < 4; ++r) tm[r] = fmaxf(tm[r], __shfl_xor(tm[r], d));

  f32x4 mnew, sf;
#pragma unroll
  for (int r = 0; r < 4; ++r) {
    mnew[r] = fmaxf(m_s[r], tm[r]);
    sf[r] = __builtin_amdgcn_exp2f(m_s[r] - mnew[r]);
  }
  m_s = mnew;

  f32x4 psum = {0.f, 0.f, 0.f, 0.f};
#pragma unroll
  for (int f = 0; f < 4; ++f)
#pragma unroll
    for (int r = 0; r < 4; ++r) {
      const float p = __builtin_amdgcn_exp2f(s[f][r] - mnew[r]);
      s[f][r] = p;
      psum[r] += p;
    }
#pragma unroll
  for (int r = 0; r < 4; ++r) l_s[r] = l_s[r] * sf[r] + psum[r];
#pragma unroll
  for (int jd = 0; jd < 4; ++jd)
#pragma unroll
    for (int r = 0; r < 4; ++r) o_s[jd][r] *= sf[r];

  // P -> per-wave LDS [16 q][64 kv] (swizzled) for MFMA A-fragment reads
#pragma unroll
  for (int f = 0; f < 4; ++f)
#pragma unroll
    for (int r = 0; r < 4; ++r)
      Pw[(g * 4 + r) * 64 + ((f * 16 + c) ^ (((g * 4 + r) & 7) << 3))] = (bf16_t)s[f][r];

  // O += P @ V
  bf16x8 pa[2];
#pragma unroll
  for (int kk = 0; kk < 2; ++kk)
    pa[kk] = *(const bf16x8*)&Pw[c * 64 + ((kk * 32 + g * 8) ^ sc)];
#pragma unroll
  for (int jd = 0; jd < 4; ++jd) {
    bf16x8 v0 = *(const bf16x8*)&Vt[(jd * 16 + c) * 64 + ((0 + g * 8) ^ sc)];
    bf16x8 v1 = *(const bf16x8*)&Vt[(jd * 16 + c) * 64 + ((32 + g * 8) ^ sc)];
    o_s[jd] = __builtin_amdgcn_mfma_f32_16x16x32_bf16(pa[0], v0, o_s[jd], 0, 0, 0);
    o_s[jd] = __builtin_amdgcn_mfma_f32_16x16x32_bf16(pa[1], v1, o_s[jd], 0, 0, 0);
  }
}

__global__ void __launch_bounds__(256, 4)
attn_kernel(const bf16_t* __restrict__ q, const bf16_t* __restrict__ k,
            const bf16_t* __restrict__ rk, const bf16_t* __restrict__ vT,
            const bf16_t* __restrict__ rvT, const int* __restrict__ mask,
            bf16_t* __restrict__ x) {
  __shared__ bf16_t Ks[64 * 64], RKs[64 * 64], Vs[64 * 64], RVs[64 * 64]; // 32KB
  __shared__ bf16_t Ps[4][16 * 64];                                      // 8KB

  const int tid = threadIdx.x;
  const int lane = tid & 63;
  const int w = tid >> 6;
  const int g = lane >> 4, c = lane & 15;
  const int bid = blockIdx.x;
  const int lid = (bid & 7) * 128 + (bid >> 3);  // T1 swizzle (1024 % 8 == 0)
  const int qt = lid & 15;
  const int bh = lid >> 4;
  const int b = bh >> 4, h = bh & 15;
  const int q0 = qt * 64;

  const bf16_t* qp = q + (size_t)bh * SEQ * DKH;
  const bf16_t* kp = k + (size_t)bh * SEQ * DKH;
  const bf16_t* rkp = rk + (size_t)bh * SEQ * DKH;
  const bf16_t* vp = vT + (size_t)bh * DKH * SEQ;
  const bf16_t* rvp = rvT + (size_t)bh * DKH * SEQ;
  const int* mp = mask + b * SEQ;
  const int lrow = lane >> 3;
  const int lcol = ((lane & 7) * 8) ^ ((lane >> 3) << 3);  // pre-swizzled source col

  // Q fragments in registers (wave owns 16 q-rows)
  bf16x8 qf[2];
#pragma unroll
  for (int kk = 0; kk < 2; ++kk)
    qf[kk] = *(const bf16x8*)(qp + (size_t)(q0 + w * 16 + c) * DKH + kk * 32 + g * 8);

  f32x4 ov[4] = {}, orl[4] = {};
  f32x4 mv = {NEG_INF, NEG_INF, NEG_INF, NEG_INF}, mr = mv;
  f32x4 lv = {0.f, 0.f, 0.f, 0.f}, lr = lv;

  for (int t = 0; t < 16; ++t) {
    const int kv0 = t * 64;
    if (t) __syncthreads();   // previous compute done before overwriting tiles
#pragma unroll
    for (int p = 0; p < 2; ++p) {
      const int row = w * 16 + p * 8;
      gload_lds16(kp  + (size_t)(kv0 + row + lrow) * DKH + lcol, &Ks[row * 64]);
      gload_lds16(rkp + (size_t)(kv0 + row + lrow) * DKH + lcol, &RKs[row * 64]);
      gload_lds16(vp  + (size_t)(row + lrow) * SEQ + kv0 + lcol, &Vs[row * 64]);
      gload_lds16(rvp + (size_t)(row + lrow) * SEQ + kv0 + lcol, &RVs[row * 64]);
    }
    __syncthreads();          // tiles ready (TLP across 4 blocks/CU hides this)

    int mk[4];
#pragma unroll
    for (int f = 0; f < 4; ++f) mk[f] = mp[kv0 + f * 16 + c];

    attn_step(Ks,  Vs,  Ps[w], qf, mk, mv, lv, ov,  lane);
    attn_step(RKs, RVs, Ps[w], qf, mk, mr, lr, orl, lane);
  }

  // reduce per-lane partial softmax denominators across the 16 columns
#pragma unroll
  for (int d = 1; d < 16; d <<= 1)
#pragma unroll
    for (int r = 0; r < 4; ++r) {
      lv[r] += __shfl_xor(lv[r], d);
      lr[r] += __shfl_xor(lr[r], d);
    }

  bf16_t* xb = x + (size_t)b * SEQ * DMODEL + (size_t)h * DKH;
  f32x4 rlv, rlr;
#pragma unroll
  for (int r = 0; r < 4; ++r) { rlv[r] = 1.0f / lv[r]; rlr[r] = 1.0f / lr[r]; }
#pragma unroll
  for (int jd = 0; jd < 4; ++jd)
#pragma unroll
    for (int r = 0; r < 4; ++r) {
      const int qrow = q0 + w * 16 + g * 4 + r;
      const float val = ov[jd][r] * rlv[r] + orl[jd][r] * rlr[r];
      xb[(size_t)qrow * DMODEL + jd * 16 + c] = (bf16_t)val;
    }
}

// ---------------- host launch ---------------------------------------------
extern "C" void kernel_launch(void* const* d_in, const int* in_sizes, int n_in,
                              void* d_out, int out_size, void* d_ws, size_t ws_size,
                              hipStream_t stream) {
  (void)in_sizes; (void)n_in; (void)out_size; (void)ws_size;
  const float* query = (const float*)d_in[0];
  const float* key_  = (const float*)d_in[1];
  const float* value = (const float*)d_in[2];
  const float* weak  = (const float*)d_in[3];
  const int*   mask  = (const int*)d_in[4];
  const float* Wq  = (const float*)d_in[5];  const float* bq  = (const float*)d_in[6];
  const float* Wk  = (const float*)d_in[7];  const float* bk  = (const float*)d_in[8];
  const float* Wv  = (const float*)d_in[9];  const float* bv  = (const float*)d_in[10];
  const float* Wrk = (const float*)d_in[11]; const float* brk = (const float*)d_in[12];
  const float* Wrv = (const float*)d_in[13]; const float* brv = (const float*)d_in[14];
  const float* Wo  = (const float*)d_in[15]; const float* bo  = (const float*)d_in[16];

  char* ws = (char*)d_ws;
  size_t off = 0;
  auto alloc = [&](size_t bytes) {
    void* p = ws + off;
    off += (bytes + 255) & ~(size_t)255;
    return p;
  };
  const size_t SZ_X = NXE * sizeof(bf16_t); // 8 MB (256-aligned -> contiguous)
  const size_t SZ_W = NWE * sizeof(bf16_t); // 2 MB

  // X segments contiguous (q,k,v,r), W segments contiguous (q,k,v,rk,rv,o),
  // proj outputs contiguous (qh,kh,rkh,vTh,rvTh) -- proj_gemm indexes by base.
  bf16_t* Xq = (bf16_t*)alloc(SZ_X);
  bf16_t* Xk = (bf16_t*)alloc(SZ_X);
  bf16_t* Xv = (bf16_t*)alloc(SZ_X);
  bf16_t* Xr = (bf16_t*)alloc(SZ_X);
  bf16_t* Wqb  = (bf16_t*)alloc(SZ_W);
  bf16_t* Wkb  = (bf16_t*)alloc(SZ_W);
  bf16_t* Wvb  = (bf16_t*)alloc(SZ_W);
  bf16_t* Wrkb = (bf16_t*)alloc(SZ_W);
  bf16_t* Wrvb = (bf16_t*)alloc(SZ_W);
  bf16_t* Wob  = (bf16_t*)alloc(SZ_W);
  bf16_t* qh   = (bf16_t*)alloc(SZ_X);
  bf16_t* kh   = (bf16_t*)alloc(SZ_X);
  bf16_t* rkh  = (bf16_t*)alloc(SZ_X);
  bf16_t* vTh  = (bf16_t*)alloc(SZ_X);
  bf16_t* rvTh = (bf16_t*)alloc(SZ_X);
  bf16_t* xh   = (bf16_t*)alloc(SZ_X);
  (void)Xk; (void)Xv; (void)Xr; (void)Wkb; (void)Wvb; (void)Wrkb; (void)Wrvb;
  (void)kh; (void)rkh; (void)vTh; (void)rvTh;

  // f32 -> bf16
  cvt_multi<<<dim3(4096, 4), 256, 0, stream>>>(query, key_, value, weak, nullptr, nullptr,
                                               Xq, Xk, Xv, Xr, nullptr, nullptr,
                                               NB * SEQ * DMODEL);
  cvt_multi<<<dim3(1024, 6), 256, 0, stream>>>(Wq, Wk, Wv, Wrk, Wrv, Wo,
                                               Wqb, Wkb, Wvb, Wrkb, Wrvb, Wob,
                                               DMODEL * DMODEL);

  // all 5 projections in one grouped dispatch (2560 blocks = 10/CU rounds)
  proj_gemm<<<dim3(2560), 256, 0, stream>>>(Xq, Wqb, qh, bq, bk, bv, brk, brv);

  // fused dual attention: 1024 blocks = 4/CU
  attn_kernel<<<dim3(1024), 256, 0, stream>>>(qh, kh, rkh, vTh, rvTh, mask, xh);

  // output projection -> f32 d_out
  out_gemm<<<dim3(512), 256, 0, stream>>>(xh, Wob, bo, (float*)d_out);
}

// Round 5
// 181.931 us; speedup vs baseline: 1.3435x; 1.1832x over previous
//
#include <hip/hip_runtime.h>
#include <stdint.h>

#define NB 4
#define NH 16
#define DKH 64
#define DMODEL 1024
#define SEQ 1024
#define SCALE 0.125f
#define NEG_INF -1.0e9f
#define K2E 0.18033688011112042f  // SCALE * log2(e): softmax in exp2 domain

typedef __bf16 bf16_t;
typedef __bf16 bf16x8 __attribute__((ext_vector_type(8)));
typedef __bf16 bf16x4v __attribute__((ext_vector_type(4)));
typedef float f32x4 __attribute__((ext_vector_type(4)));

typedef const uint32_t __attribute__((address_space(1)))* gas_ptr;
typedef uint32_t __attribute__((address_space(3)))* las_ptr;

// async global->LDS, 16B per lane, dest = wave-uniform base + lane*16
__device__ __forceinline__ void gload_lds16(const void* g, void* l) {
  __builtin_amdgcn_global_load_lds((gas_ptr)g, (las_ptr)l, 16, 0, 0);
}

// T2 XOR swizzle for [R][64] bf16 tiles (128B rows): element col ^= (row&7)<<3.
// Staging keeps LDS dest linear and pre-swizzles the GLOBAL source column;
// all LDS reads / reg->LDS writes apply the same XOR (both-sides involution).
// Proven: SQ_LDS_BANK_CONFLICT 1.99e7 -> 0 (R1->R2).
//
// __launch_bounds__ NOTE (R4 post-mortem): (256,4) made the allocator squeeze
// to 64 VGPR and spill (~230MB scratch traffic, WRITE_SIZE 8->118MB). (256,2)
// is proven sane (112-128 VGPR, no spill). Do not use min-waves > 2 here.

// ---------------- f32 -> bf16 conversion (select tensor by blockIdx.y) ----
__global__ void cvt_multi(const float* __restrict__ i0, const float* __restrict__ i1,
                          const float* __restrict__ i2, const float* __restrict__ i3,
                          const float* __restrict__ i4, const float* __restrict__ i5,
                          bf16_t* o0, bf16_t* o1, bf16_t* o2, bf16_t* o3, bf16_t* o4, bf16_t* o5,
                          int n) {
  const int t = blockIdx.y;
  const float* in = (t == 0) ? i0 : (t == 1) ? i1 : (t == 2) ? i2 : (t == 3) ? i3 : (t == 4) ? i4 : i5;
  bf16_t* out = (t == 0) ? o0 : (t == 1) ? o1 : (t == 2) ? o2 : (t == 3) ? o3 : (t == 4) ? o4 : o5;
  const int idx = (blockIdx.x * 256 + threadIdx.x) * 4;
  if (idx >= n) return;
  const float4 v = *(const float4*)(in + idx);
  bf16x4v p;
  p[0] = (bf16_t)v.x; p[1] = (bf16_t)v.y; p[2] = (bf16_t)v.z; p[3] = (bf16_t)v.w;
  *(bf16x4v*)(out + idx) = p;
}

// ---------------- grouped projection GEMM ---------------------------------
// 5 segments (q,k,v,rk,rv), each Y = A @ W^T + bias, [4096x1024]x[1024x1024].
// Tile 128x64, BK=64, 4 waves (2x2), single-buffered LDS (24KB).
#define NXE ((size_t)NB * SEQ * DMODEL)      // elements per X/out segment
#define NWE ((size_t)DMODEL * DMODEL)
__global__ void __launch_bounds__(256, 2)
proj_gemm(const bf16_t* __restrict__ Xbase, const bf16_t* __restrict__ Wbase,
          bf16_t* __restrict__ Obase,
          const float* __restrict__ b0, const float* __restrict__ b1,
          const float* __restrict__ b2, const float* __restrict__ b3,
          const float* __restrict__ b4) {
  __shared__ bf16_t As[128 * 64];
  __shared__ bf16_t Bs[64 * 64];
  const int tid = threadIdx.x;
  const int lane = tid & 63;
  const int w = tid >> 6;
  const int wm = w >> 1, wn = w & 1;
  const int g = lane >> 4, c = lane & 15;
  // T1 bijective XCD swizzle: 2560 % 8 == 0, cpx = 320
  const int bid = blockIdx.x;
  const int lid = (bid & 7) * 320 + (bid >> 3);
  const int seg = lid >> 9;                 // 0..4
  const int rr = lid & 511;
  const int bm = rr >> 4, bn = rr & 15;     // 32 x 16 tiles
  const int m0 = bm * 128, n0 = bn * 64;
  const int lrow = lane >> 3;
  const int lcol = ((lane & 7) * 8) ^ ((lane >> 3) << 3);  // pre-swizzled source col
  const int sc = (c & 7) << 3;                             // read-side XOR

  const bf16_t* A = Xbase + (size_t)((seg < 3) ? seg : 3) * NXE;
  const bf16_t* W = Wbase + (size_t)seg * NWE;
  const int ooff = (seg == 0) ? 0 : (seg == 1) ? 1 : (seg == 2) ? 3 : (seg == 3) ? 2 : 4;
  bf16_t* out = Obase + (size_t)ooff * NXE;
  const float* bias = (seg == 0) ? b0 : (seg == 1) ? b1 : (seg == 2) ? b2 : (seg == 3) ? b3 : b4;
  const bool tr = (seg == 2) || (seg == 4);

  f32x4 acc[4][2] = {};

  for (int kt = 0; kt < DMODEL; kt += 64) {
#pragma unroll
    for (int p = 0; p < 4; ++p) {
      const int row = w * 32 + p * 8;
      gload_lds16(A + (size_t)(m0 + row + lrow) * DMODEL + kt + lcol, &As[row * 64]);
    }
#pragma unroll
    for (int p = 0; p < 2; ++p) {
      const int row = w * 16 + p * 8;
      gload_lds16(W + (size_t)(n0 + row + lrow) * DMODEL + kt + lcol, &Bs[row * 64]);
    }
    __syncthreads();
    bf16x8 af[4][2], bfr[2][2];
#pragma unroll
    for (int i = 0; i < 4; ++i)
#pragma unroll
      for (int kk = 0; kk < 2; ++kk)
        af[i][kk] = *(const bf16x8*)&As[(wm * 64 + i * 16 + c) * 64 + ((kk * 32 + g * 8) ^ sc)];
#pragma unroll
    for (int j = 0; j < 2; ++j)
#pragma unroll
      for (int kk = 0; kk < 2; ++kk)
        bfr[j][kk] = *(const bf16x8*)&Bs[(wn * 32 + j * 16 + c) * 64 + ((kk * 32 + g * 8) ^ sc)];
#pragma unroll
    for (int i = 0; i < 4; ++i)
#pragma unroll
      for (int j = 0; j < 2; ++j) {
        acc[i][j] = __builtin_amdgcn_mfma_f32_16x16x32_bf16(af[i][0], bfr[j][0], acc[i][j], 0, 0, 0);
        acc[i][j] = __builtin_amdgcn_mfma_f32_16x16x32_bf16(af[i][1], bfr[j][1], acc[i][j], 0, 0, 0);
      }
    __syncthreads();
  }

  float bv2[2];
#pragma unroll
  for (int j = 0; j < 2; ++j) bv2[j] = bias[n0 + wn * 32 + j * 16 + c];

#pragma unroll
  for (int i = 0; i < 4; ++i) {
    const int mrow = m0 + wm * 64 + i * 16 + g * 4;   // C-layout: row = g*4 + r
    const int b_ = mrow >> 10, l_ = mrow & 1023;
#pragma unroll
    for (int j = 0; j < 2; ++j) {
      const int n = n0 + wn * 32 + j * 16 + c;        // C-layout: col = lane&15
      const int h_ = n >> 6, dk_ = n & 63;
      if (!tr) {
#pragma unroll
        for (int r = 0; r < 4; ++r)
          out[((size_t)(b_ * NH + h_) * SEQ + l_ + r) * DKH + dk_] =
              (bf16_t)(acc[i][j][r] + bv2[j]);
      } else { // transposed [B,H,DK,L]; 4 consecutive l -> packed 8B store
        bf16x4v pk;
#pragma unroll
        for (int r = 0; r < 4; ++r) pk[r] = (bf16_t)(acc[i][j][r] + bv2[j]);
        *(bf16x4v*)&out[((size_t)(b_ * NH + h_) * DKH + dk_) * SEQ + l_] = pk;
      }
    }
  }
}

// ---------------- output projection GEMM (f32 out) -------------------------
__global__ void __launch_bounds__(256, 2)
out_gemm(const bf16_t* __restrict__ A, const bf16_t* __restrict__ W,
         const float* __restrict__ bias, float* __restrict__ out) {
  __shared__ bf16_t As[128 * 64];
  __shared__ bf16_t Bs[64 * 64];
  const int tid = threadIdx.x;
  const int lane = tid & 63;
  const int w = tid >> 6;
  const int wm = w >> 1, wn = w & 1;
  const int g = lane >> 4, c = lane & 15;
  const int bid = blockIdx.x;
  const int lid = (bid & 7) * 64 + (bid >> 3);   // T1 swizzle (512 % 8 == 0)
  const int bm = lid >> 4, bn = lid & 15;
  const int m0 = bm * 128, n0 = bn * 64;
  const int lrow = lane >> 3;
  const int lcol = ((lane & 7) * 8) ^ ((lane >> 3) << 3);
  const int sc = (c & 7) << 3;

  f32x4 acc[4][2] = {};

  for (int kt = 0; kt < DMODEL; kt += 64) {
#pragma unroll
    for (int p = 0; p < 4; ++p) {
      const int row = w * 32 + p * 8;
      gload_lds16(A + (size_t)(m0 + row + lrow) * DMODEL + kt + lcol, &As[row * 64]);
    }
#pragma unroll
    for (int p = 0; p < 2; ++p) {
      const int row = w * 16 + p * 8;
      gload_lds16(W + (size_t)(n0 + row + lrow) * DMODEL + kt + lcol, &Bs[row * 64]);
    }
    __syncthreads();
    bf16x8 af[4][2], bfr[2][2];
#pragma unroll
    for (int i = 0; i < 4; ++i)
#pragma unroll
      for (int kk = 0; kk < 2; ++kk)
        af[i][kk] = *(const bf16x8*)&As[(wm * 64 + i * 16 + c) * 64 + ((kk * 32 + g * 8) ^ sc)];
#pragma unroll
    for (int j = 0; j < 2; ++j)
#pragma unroll
      for (int kk = 0; kk < 2; ++kk)
        bfr[j][kk] = *(const bf16x8*)&Bs[(wn * 32 + j * 16 + c) * 64 + ((kk * 32 + g * 8) ^ sc)];
#pragma unroll
    for (int i = 0; i < 4; ++i)
#pragma unroll
      for (int j = 0; j < 2; ++j) {
        acc[i][j] = __builtin_amdgcn_mfma_f32_16x16x32_bf16(af[i][0], bfr[j][0], acc[i][j], 0, 0, 0);
        acc[i][j] = __builtin_amdgcn_mfma_f32_16x16x32_bf16(af[i][1], bfr[j][1], acc[i][j], 0, 0, 0);
      }
    __syncthreads();
  }

  float bv2[2];
#pragma unroll
  for (int j = 0; j < 2; ++j) bv2[j] = bias[n0 + wn * 32 + j * 16 + c];
#pragma unroll
  for (int i = 0; i < 4; ++i) {
    const int mrow = m0 + wm * 64 + i * 16 + g * 4;
#pragma unroll
    for (int j = 0; j < 2; ++j) {
      const int n = n0 + wn * 32 + j * 16 + c;
#pragma unroll
      for (int r = 0; r < 4; ++r)
        out[(size_t)(mrow + r) * DMODEL + n] = acc[i][j][r] + bv2[j];
    }
  }
}

// ---------------- fused dual flash attention (swapped QK^T) ----------------
// S^T = mfma(A=K, B=Q): lane (g,c) holds S[kv=f*16+g*4+r][q=c] -> softmax is
// lane-local (15 fmax) + 2 cross-g shfl; m/l are scalars. PV computed as
// O^T = mfma(A=V^T, B=P). P round-trips per-wave LDS as 4x ds_write_b64.
__device__ __forceinline__ void attn_step(
    const bf16_t* __restrict__ Kt, const bf16_t* __restrict__ Vt,
    bf16_t* __restrict__ Pw, const bf16x8 (&qf)[2], const int4 (&mk)[4],
    float& m_s, float& l_s, f32x4 (&o_s)[4], int lane) {
  const int g = lane >> 4, c = lane & 15;
  const int sc = (c & 7) << 3;

  f32x4 s[4];
#pragma unroll
  for (int f = 0; f < 4; ++f) {
    const bf16x8 k0 = *(const bf16x8*)&Kt[(f * 16 + c) * 64 + ((g * 8) ^ sc)];
    const bf16x8 k1 = *(const bf16x8*)&Kt[(f * 16 + c) * 64 + ((32 + g * 8) ^ sc)];
    f32x4 a = {0.f, 0.f, 0.f, 0.f};
    a = __builtin_amdgcn_mfma_f32_16x16x32_bf16(k0, qf[0], a, 0, 0, 0);
    a = __builtin_amdgcn_mfma_f32_16x16x32_bf16(k1, qf[1], a, 0, 0, 0);
    s[f] = a;
  }

  // mask + scale into exp2 domain (masked -> NEG_INF; kv=0 always valid)
#pragma unroll
  for (int f = 0; f < 4; ++f) {
    s[f][0] = (mk[f].x == 0) ? NEG_INF : s[f][0] * K2E;
    s[f][1] = (mk[f].y == 0) ? NEG_INF : s[f][1] * K2E;
    s[f][2] = (mk[f].z == 0) ? NEG_INF : s[f][2] * K2E;
    s[f][3] = (mk[f].w == 0) ? NEG_INF : s[f][3] * K2E;
  }

  // row max: 15 local fmax + cross-g reduce (lanes {c,c+16,c+32,c+48})
  float tm = fmaxf(fmaxf(s[0][0], s[0][1]), fmaxf(s[0][2], s[0][3]));
#pragma unroll
  for (int f = 1; f < 4; ++f)
    tm = fmaxf(tm, fmaxf(fmaxf(s[f][0], s[f][1]), fmaxf(s[f][2], s[f][3])));
  tm = fmaxf(tm, __shfl_xor(tm, 16));
  tm = fmaxf(tm, __shfl_xor(tm, 32));

  const float mnew = fmaxf(m_s, tm);
  const float sf = __builtin_amdgcn_exp2f(m_s - mnew);
  m_s = mnew;

  float pf[4];
#pragma unroll
  for (int f = 0; f < 4; ++f) {
#pragma unroll
    for (int r = 0; r < 4; ++r) s[f][r] = __builtin_amdgcn_exp2f(s[f][r] - mnew);
    pf[f] = (s[f][0] + s[f][1]) + (s[f][2] + s[f][3]);
  }
  l_s = l_s * sf + ((pf[0] + pf[1]) + (pf[2] + pf[3]));  // per-lane partial
#pragma unroll
  for (int jd = 0; jd < 4; ++jd)
#pragma unroll
    for (int r = 0; r < 4; ++r) o_s[jd][r] *= sf;

  // P -> per-wave LDS [16 q][64 kv] (swizzled; row=c so XOR = sc), 8B packs
#pragma unroll
  for (int f = 0; f < 4; ++f) {
    bf16x4v pk;
#pragma unroll
    for (int r = 0; r < 4; ++r) pk[r] = (bf16_t)s[f][r];
    *(bf16x4v*)&Pw[c * 64 + ((f * 16 + g * 4) ^ sc)] = pk;
  }

  // O^T += V^T @ P (A = V^T frag rows d, B = P frag cols q)
  const bf16x8 pa0 = *(const bf16x8*)&Pw[c * 64 + ((g * 8) ^ sc)];
  const bf16x8 pa1 = *(const bf16x8*)&Pw[c * 64 + ((32 + g * 8) ^ sc)];
#pragma unroll
  for (int jd = 0; jd < 4; ++jd) {
    const bf16x8 v0 = *(const bf16x8*)&Vt[(jd * 16 + c) * 64 + ((g * 8) ^ sc)];
    const bf16x8 v1 = *(const bf16x8*)&Vt[(jd * 16 + c) * 64 + ((32 + g * 8) ^ sc)];
    o_s[jd] = __builtin_amdgcn_mfma_f32_16x16x32_bf16(v0, pa0, o_s[jd], 0, 0, 0);
    o_s[jd] = __builtin_amdgcn_mfma_f32_16x16x32_bf16(v1, pa1, o_s[jd], 0, 0, 0);
  }
}

__global__ void __launch_bounds__(256, 2)
attn_kernel(const bf16_t* __restrict__ q, const bf16_t* __restrict__ k,
            const bf16_t* __restrict__ rk, const bf16_t* __restrict__ vT,
            const bf16_t* __restrict__ rvT, const int* __restrict__ mask,
            bf16_t* __restrict__ x) {
  __shared__ bf16_t Ks[64 * 64], RKs[64 * 64], Vs[64 * 64], RVs[64 * 64]; // 32KB
  __shared__ bf16_t Ps[4][16 * 64];                                      // 8KB

  const int tid = threadIdx.x;
  const int lane = tid & 63;
  const int w = tid >> 6;
  const int g = lane >> 4, c = lane & 15;
  const int bid = blockIdx.x;
  const int lid = (bid & 7) * 128 + (bid >> 3);  // T1 swizzle (1024 % 8 == 0)
  const int qt = lid & 15;
  const int bh = lid >> 4;
  const int b = bh >> 4, h = bh & 15;
  const int q0 = qt * 64;

  const bf16_t* qp = q + (size_t)bh * SEQ * DKH;
  const bf16_t* kp = k + (size_t)bh * SEQ * DKH;
  const bf16_t* rkp = rk + (size_t)bh * SEQ * DKH;
  const bf16_t* vp = vT + (size_t)bh * DKH * SEQ;
  const bf16_t* rvp = rvT + (size_t)bh * DKH * SEQ;
  const int* mp = mask + b * SEQ;
  const int lrow = lane >> 3;
  const int lcol = ((lane & 7) * 8) ^ ((lane >> 3) << 3);  // pre-swizzled source col

  // Q fragments in registers (wave owns 16 q-rows; B-operand layout)
  bf16x8 qf[2];
#pragma unroll
  for (int kk = 0; kk < 2; ++kk)
    qf[kk] = *(const bf16x8*)(qp + (size_t)(q0 + w * 16 + c) * DKH + kk * 32 + g * 8);

  f32x4 ov[4] = {}, orl[4] = {};
  float mv = NEG_INF, mr = NEG_INF, lv = 0.f, lr = 0.f;

  for (int t = 0; t < 16; ++t) {
    const int kv0 = t * 64;
    if (t) __syncthreads();   // previous compute done before overwriting tiles
#pragma unroll
    for (int p = 0; p < 2; ++p) {
      const int row = w * 16 + p * 8;
      gload_lds16(kp  + (size_t)(kv0 + row + lrow) * DKH + lcol, &Ks[row * 64]);
      gload_lds16(rkp + (size_t)(kv0 + row + lrow) * DKH + lcol, &RKs[row * 64]);
      gload_lds16(vp  + (size_t)(row + lrow) * SEQ + kv0 + lcol, &Vs[row * 64]);
      gload_lds16(rvp + (size_t)(row + lrow) * SEQ + kv0 + lcol, &RVs[row * 64]);
    }
    __syncthreads();          // tiles ready (TLP across blocks hides this)

    int4 mk4[4];
#pragma unroll
    for (int f = 0; f < 4; ++f) mk4[f] = *(const int4*)&mp[kv0 + f * 16 + g * 4];

    attn_step(Ks,  Vs,  Ps[w], qf, mk4, mv, lv, ov,  lane);
    attn_step(RKs, RVs, Ps[w], qf, mk4, mr, lr, orl, lane);
  }

  // denominators: reduce per-lane partials across the 4 g-groups
  lv += __shfl_xor(lv, 16); lv += __shfl_xor(lv, 32);
  lr += __shfl_xor(lr, 16); lr += __shfl_xor(lr, 32);
  const float rlv = 1.0f / lv, rlr = 1.0f / lr;

  bf16_t* xb = x + (size_t)b * SEQ * DMODEL + (size_t)h * DKH;
  const int qrow = q0 + w * 16 + c;
#pragma unroll
  for (int jd = 0; jd < 4; ++jd) {
    bf16x4v pk;
#pragma unroll
    for (int r = 0; r < 4; ++r)
      pk[r] = (bf16_t)(ov[jd][r] * rlv + orl[jd][r] * rlr);
    *(bf16x4v*)&xb[(size_t)qrow * DMODEL + jd * 16 + g * 4] = pk;
  }
}

// ---------------- host launch ---------------------------------------------
extern "C" void kernel_launch(void* const* d_in, const int* in_sizes, int n_in,
                              void* d_out, int out_size, void* d_ws, size_t ws_size,
                              hipStream_t stream) {
  (void)in_sizes; (void)n_in; (void)out_size; (void)ws_size;
  const float* query = (const float*)d_in[0];
  const float* key_  = (const float*)d_in[1];
  const float* value = (const float*)d_in[2];
  const float* weak  = (const float*)d_in[3];
  const int*   mask  = (const int*)d_in[4];
  const float* Wq  = (const float*)d_in[5];  const float* bq  = (const float*)d_in[6];
  const float* Wk  = (const float*)d_in[7];  const float* bk  = (const float*)d_in[8];
  const float* Wv  = (const float*)d_in[9];  const float* bv  = (const float*)d_in[10];
  const float* Wrk = (const float*)d_in[11]; const float* brk = (const float*)d_in[12];
  const float* Wrv = (const float*)d_in[13]; const float* brv = (const float*)d_in[14];
  const float* Wo  = (const float*)d_in[15]; const float* bo  = (const float*)d_in[16];

  char* ws = (char*)d_ws;
  size_t off = 0;
  auto alloc = [&](size_t bytes) {
    void* p = ws + off;
    off += (bytes + 255) & ~(size_t)255;
    return p;
  };
  const size_t SZ_X = NXE * sizeof(bf16_t); // 8 MB (256-aligned -> contiguous)
  const size_t SZ_W = NWE * sizeof(bf16_t); // 2 MB

  // X segments contiguous (q,k,v,r), W segments contiguous (q,k,v,rk,rv,o),
  // proj outputs contiguous (qh,kh,rkh,vTh,rvTh) -- proj_gemm indexes by base.
  bf16_t* Xq = (bf16_t*)alloc(SZ_X);
  bf16_t* Xk = (bf16_t*)alloc(SZ_X);
  bf16_t* Xv = (bf16_t*)alloc(SZ_X);
  bf16_t* Xr = (bf16_t*)alloc(SZ_X);
  bf16_t* Wqb  = (bf16_t*)alloc(SZ_W);
  bf16_t* Wkb  = (bf16_t*)alloc(SZ_W);
  bf16_t* Wvb  = (bf16_t*)alloc(SZ_W);
  bf16_t* Wrkb = (bf16_t*)alloc(SZ_W);
  bf16_t* Wrvb = (bf16_t*)alloc(SZ_W);
  bf16_t* Wob  = (bf16_t*)alloc(SZ_W);
  bf16_t* qh   = (bf16_t*)alloc(SZ_X);
  bf16_t* kh   = (bf16_t*)alloc(SZ_X);
  bf16_t* rkh  = (bf16_t*)alloc(SZ_X);
  bf16_t* vTh  = (bf16_t*)alloc(SZ_X);
  bf16_t* rvTh = (bf16_t*)alloc(SZ_X);
  bf16_t* xh   = (bf16_t*)alloc(SZ_X);
  (void)Xk; (void)Xv; (void)Xr; (void)Wkb; (void)Wvb; (void)Wrkb; (void)Wrvb;
  (void)kh; (void)rkh; (void)vTh; (void)rvTh;

  // f32 -> bf16
  cvt_multi<<<dim3(4096, 4), 256, 0, stream>>>(query, key_, value, weak, nullptr, nullptr,
                                               Xq, Xk, Xv, Xr, nullptr, nullptr,
                                               NB * SEQ * DMODEL);
  cvt_multi<<<dim3(1024, 6), 256, 0, stream>>>(Wq, Wk, Wv, Wrk, Wrv, Wo,
                                               Wqb, Wkb, Wvb, Wrkb, Wrvb, Wob,
                                               DMODEL * DMODEL);

  // all 5 projections in one grouped dispatch (2560 blocks)
  proj_gemm<<<dim3(2560), 256, 0, stream>>>(Xq, Wqb, qh, bq, bk, bv, brk, brv);

  // fused dual attention: 1024 blocks
  attn_kernel<<<dim3(1024), 256, 0, stream>>>(qh, kh, rkh, vTh, rvTh, mask, xh);

  // output projection -> f32 d_out
  out_gemm<<<dim3(512), 256, 0, stream>>>(xh, Wob, bo, (float*)d_out);
}